// Round 8
// baseline (148.940 us; speedup 1.0000x reference)
//
#include <hip/hip_runtime.h>

// InteractionNetwork B=4, N=256, D=128, L=3.
// agg = (sum_j adj_ij * relu(xi_i + xj_j)) @ ew2 + rowsum(adj)_i * eb2   (eb1 folded into xi)
// R4 lesson: per-dispatch overhead dominates (7 kernels ~20us each, occupancy-invariant).
// R5: fuse agg+MLP+next-proj into one klayer (block owns 2 rows, full j-loop in-block);
// double-buffered xi/xj breaks the intra-dispatch WAR race. 4 dispatches total.

#define DD 128
#define NN 256

// ---------------- kproj: grid 512, block 256; 2 rows/block; k split 2x64 (hh)
__global__ __launch_bounds__(256, 4) void kproj(
    const float* __restrict__ x, const float* __restrict__ w,
    const float* __restrict__ b1, float* __restrict__ xi, float* __restrict__ xj)
{
  const int r0 = blockIdx.x * 2;
  const int t = threadIdx.x, c = t & 127, hh = t >> 7;
  __shared__ float xs[2][DD];
  __shared__ float red[2][2][2][DD];  // [stream][row][hh][c]
  ((float*)xs)[t] = x[r0 * DD + t];
  __syncthreads();
  float ai[2] = {0.f, 0.f}, aj[2] = {0.f, 0.f};
  const int k0 = hh * 64;
#pragma unroll 8
  for (int kk = 0; kk < 64; ++kk) {
    const int k = k0 + kk;
    const float wiv = w[k * DD + c], wjv = w[(DD + k) * DD + c];
    ai[0] = fmaf(xs[0][k], wiv, ai[0]); ai[1] = fmaf(xs[1][k], wiv, ai[1]);
    aj[0] = fmaf(xs[0][k], wjv, aj[0]); aj[1] = fmaf(xs[1][k], wjv, aj[1]);
  }
  red[0][0][hh][c] = ai[0]; red[0][1][hh][c] = ai[1];
  red[1][0][hh][c] = aj[0]; red[1][1][hh][c] = aj[1];
  __syncthreads();
  const int g = hh;
#pragma unroll
  for (int r = 0; r < 2; ++r) {
    const float s = red[g][r][0][c] + red[g][r][1][c];
    if (g == 0) xi[(r0 + r) * DD + c] = s + b1[c];
    else        xj[(r0 + r) * DD + c] = s;
  }
}

// ---------------- klayer: grid 512, block 256; block owns rows r0,r0+1 end-to-end.
// agg (full 256-j loop) -> agg@ew2+rowsum*eb2 -> node MLP -> residual -> next proj.
__global__ __launch_bounds__(256, 4) void klayer(
    const float* __restrict__ xin, const float* __restrict__ adj,
    const float* __restrict__ xi, const float* __restrict__ xj,
    const float* __restrict__ ew2, const float* __restrict__ eb2,
    const float* __restrict__ nw1, const float* __restrict__ nb1,
    const float* __restrict__ nw2, const float* __restrict__ nb2,
    float* __restrict__ xout,
    const float* __restrict__ ew1n, const float* __restrict__ eb1n,
    float* __restrict__ xin_, float* __restrict__ xjn, const int has_next)
{
  const int r0 = blockIdx.x * 2;      // global row (rows never straddle a batch)
  const int b  = r0 >> 8;             // batch
  const int t = threadIdx.x, c = t & 127, hh = t >> 7;
  __shared__ float2 adj2[NN];         // [j] -> (row0, row1)
  __shared__ float xs[2][DD], hs[2][DD], ags[2][DD], ns[2][DD], os[2][DD];
  __shared__ float red[2][2][2][DD];  // [stream][row][hh][c]
  __shared__ float rs[2];

  // stage adj rows + x rows
  {
    const float* ap = adj + (size_t)r0 * NN;   // [b][il][*] == r0*NN
    adj2[t].x = ap[t];
    adj2[t].y = ap[NN + t];
    ((float*)xs)[t] = xin[r0 * DD + t];
  }
  __syncthreads();

  // rowsum via waves 0,1 (wave w reduces row w)
  {
    const int wv = t >> 6, lane = t & 63;
    if (wv < 2) {
      float s;
      if (wv == 0) s = adj2[lane].x + adj2[lane + 64].x + adj2[lane + 128].x + adj2[lane + 192].x;
      else         s = adj2[lane].y + adj2[lane + 64].y + adj2[lane + 128].y + adj2[lane + 192].y;
      for (int off = 32; off; off >>= 1) s += __shfl_down(s, off);
      if (lane == 0) rs[wv] = s;
    }
  }

  // agg: thread (d=c, j-half=hh) -> partial over 128 j for both rows
  {
    const float xiv0 = xi[r0 * DD + c], xiv1 = xi[(r0 + 1) * DD + c];
    float acc0 = 0.f, acc1 = 0.f;
    const float* xjp = xj + (size_t)(b * NN + hh * 128) * DD + c;
#pragma unroll 8
    for (int jj = 0; jj < 128; ++jj) {
      const float xv = xjp[(size_t)jj * DD];
      const float2 av = adj2[hh * 128 + jj];
      acc0 = fmaf(av.x, fmaxf(xiv0 + xv, 0.f), acc0);
      acc1 = fmaf(av.y, fmaxf(xiv1 + xv, 0.f), acc1);
    }
    red[0][0][hh][c] = acc0; red[0][1][hh][c] = acc1;
  }
  __syncthreads();
  { const int r = hh; hs[r][c] = red[0][r][0][c] + red[0][r][1][c]; }
  __syncthreads();

  // Phase A: a1 = hs@ew2 (-> ags) ; a2 = xs@nw1a (kept in regs for B)
  float a2[2] = {0.f, 0.f};
  {
    float a1[2] = {0.f, 0.f};
    const int k0 = hh * 64;
#pragma unroll 8
    for (int kk = 0; kk < 64; ++kk) {
      const int k = k0 + kk;
      const float w2v = ew2[k * DD + c], wav = nw1[k * DD + c];
      a1[0] = fmaf(hs[0][k], w2v, a1[0]); a1[1] = fmaf(hs[1][k], w2v, a1[1]);
      a2[0] = fmaf(xs[0][k], wav, a2[0]); a2[1] = fmaf(xs[1][k], wav, a2[1]);
    }
    red[0][0][hh][c] = a1[0]; red[0][1][hh][c] = a1[1];
  }
  __syncthreads();
  { const int r = hh;
    ags[r][c] = red[0][r][0][c] + red[0][r][1][c] + rs[r] * eb2[c]; }
  __syncthreads();

  // Phase B: a3 = ags@nw1b ; ns = relu(a2 + a3 + nb1)
  {
    float a3[2] = {0.f, 0.f};
    const int k0 = hh * 64;
#pragma unroll 8
    for (int kk = 0; kk < 64; ++kk) {
      const int k = k0 + kk;
      const float wbv = nw1[(DD + k) * DD + c];
      a3[0] = fmaf(ags[0][k], wbv, a3[0]); a3[1] = fmaf(ags[1][k], wbv, a3[1]);
    }
    red[0][0][hh][c] = a2[0] + a3[0]; red[0][1][hh][c] = a2[1] + a3[1];
  }
  __syncthreads();
  { const int r = hh;
    ns[r][c] = fmaxf(red[0][r][0][c] + red[0][r][1][c] + nb1[c], 0.f); }
  __syncthreads();

  // Phase C: upd = ns@nw2 ; xout = xin + upd + nb2
  {
    float a4[2] = {0.f, 0.f};
    const int k0 = hh * 64;
#pragma unroll 8
    for (int kk = 0; kk < 64; ++kk) {
      const int k = k0 + kk;
      const float wv = nw2[k * DD + c];
      a4[0] = fmaf(ns[0][k], wv, a4[0]); a4[1] = fmaf(ns[1][k], wv, a4[1]);
    }
    red[0][0][hh][c] = a4[0]; red[0][1][hh][c] = a4[1];
  }
  __syncthreads();
  { const int r = hh;
    const float xo = xs[r][c] + red[0][r][0][c] + red[0][r][1][c] + nb2[c];
    xout[(r0 + r) * DD + c] = xo;
    os[r][c] = xo; }
  if (!has_next) return;
  __syncthreads();

  // Phase D: next-layer projection from os -> double-buffered xi/xj
  {
    float ai[2] = {0.f, 0.f}, aj[2] = {0.f, 0.f};
    const int k0 = hh * 64;
#pragma unroll 8
    for (int kk = 0; kk < 64; ++kk) {
      const int k = k0 + kk;
      const float wiv = ew1n[k * DD + c], wjv = ew1n[(DD + k) * DD + c];
      ai[0] = fmaf(os[0][k], wiv, ai[0]); ai[1] = fmaf(os[1][k], wiv, ai[1]);
      aj[0] = fmaf(os[0][k], wjv, aj[0]); aj[1] = fmaf(os[1][k], wjv, aj[1]);
    }
    red[0][0][hh][c] = ai[0]; red[0][1][hh][c] = ai[1];
    red[1][0][hh][c] = aj[0]; red[1][1][hh][c] = aj[1];
  }
  __syncthreads();
  {
    const int g = hh;
#pragma unroll
    for (int r = 0; r < 2; ++r) {
      const float s = red[g][r][0][c] + red[g][r][1][c];
      if (g == 0) xin_[(r0 + r) * DD + c] = s + eb1n[c];
      else        xjn [(r0 + r) * DD + c] = s;
    }
  }
}

extern "C" void kernel_launch(void* const* d_in, const int* in_sizes, int n_in,
                              void* d_out, int out_size, void* d_ws, size_t ws_size,
                              hipStream_t stream) {
  const float* x0  = (const float*)d_in[0];
  const float* adj = (const float*)d_in[1];
  const float* ew1 = (const float*)d_in[2];
  const float* eb1 = (const float*)d_in[3];
  const float* ew2 = (const float*)d_in[4];
  const float* eb2 = (const float*)d_in[5];
  const float* nw1 = (const float*)d_in[6];
  const float* nb1 = (const float*)d_in[7];
  const float* nw2 = (const float*)d_in[8];
  const float* nb2 = (const float*)d_in[9];
  float* out = (float*)d_out;
  float* ws  = (float*)d_ws;

  float* xi0 = ws;                // 131072 each
  float* xj0 = ws + 131072;
  float* xi1 = ws + 262144;
  float* xj1 = ws + 393216;
  float* xA  = ws + 524288;
  float* xB  = ws + 655360;

  kproj<<<512, 256, 0, stream>>>(x0, ew1, eb1, xi0, xj0);

  const float* xins[3]  = {x0, xA, xB};
  float*       xouts[3] = {xA, xB, out};
  const float* xis[2] = {xi0, xi1};
  const float* xjs[2] = {xj0, xj1};
  float*       xiw[2] = {xi0, xi1};
  float*       xjw[2] = {xj0, xj1};
  for (int l = 0; l < 3; ++l) {
    const int cur = l & 1, nxt = cur ^ 1;
    const int ln = (l + 1 < 3) ? (l + 1) : 0;  // dummy for last layer (unused)
    klayer<<<512, 256, 0, stream>>>(
        xins[l], adj, xis[cur], xjs[cur],
        ew2 + l * DD * DD, eb2 + l * DD,
        nw1 + l * 2 * DD * DD, nb1 + l * DD,
        nw2 + l * DD * DD, nb2 + l * DD,
        xouts[l],
        ew1 + ln * 2 * DD * DD, eb1 + ln * DD,
        xiw[nxt], xjw[nxt], (l + 1 < 3) ? 1 : 0);
  }
}